// Round 11
// baseline (182.166 us; speedup 1.0000x reference)
//
#include <hip/hip_runtime.h>
#include <hip/hip_bf16.h>
#include <cmath>

#define L 96
#define L3 (L*L*L)

// B-in-LDS row stride: 456 shorts (912 B) -> measured conflict-free (R8).
#define BSTRIDE 456

typedef __attribute__((ext_vector_type(8))) short short8;
typedef __attribute__((ext_vector_type(4))) float floatx4;

__device__ __forceinline__ float eluf(float x) {
    float e = __expf(x) - 1.0f;
    return x > 0.0f ? x : e;
}

__device__ __forceinline__ unsigned short f2bf(float f) {
    __hip_bfloat16 h = __float2bfloat16(f);
    return *reinterpret_cast<unsigned short*>(&h);
}

// wrap into [0,96) for x in [-1, 97)
__device__ __forceinline__ int wrapc(int x) {
    if (x < 0) x += L;
    if (x >= L) x -= L;
    return x;
}

// ---- fused: bonds (all 3456 blocks) + weight reorder (blocks 0-83) ----
__global__ __launch_bounds__(256) void prep_kernel(
    const int* __restrict__ lx, const float* __restrict__ tet,
    const float* __restrict__ w1, const float* __restrict__ w2,
    unsigned short* __restrict__ bnd,
    unsigned short* __restrict__ Bm1, unsigned short* __restrict__ Bm2)
{
    int idx = blockIdx.x * 256 + threadIdx.x;

    // weight reorder: Bmat[N][K=448], K = tap*16 + ch, zero-padded
    if (idx < 16*448) {
        int o = idx / 448, k = idx % 448;
        int tau = k >> 4, i = k & 15;
        float v = (tau < 27 && i < 12) ? w1[tau*192 + i*16 + o] : 0.0f;
        Bm1[o*448 + k] = f2bf(v);
    }
    int j = idx - 16*448;
    if (j >= 0 && j < 32*448) {
        int o = j / 448, k = j % 448;
        int tau = k >> 4;
        int i = k & 15;
        float v = (tau < 27) ? w2[tau*512 + i*32 + o] : 0.0f;
        Bm2[o*448 + k] = f2bf(v);
    }

    // bonds: spins -> unpadded bf16 [96^3][16], ch 12-15 = 0
    int w = idx % L;
    int t = idx / L;
    int h = t % L;
    int d = t / L;

    float t00 = tet[0], t01 = tet[1], t10 = tet[2], t11 = tet[3];
    float d00 = t00*t00 + t01*t01;
    float d01 = t00*t10 + t01*t11;
    float d11 = t10*t10 + t11*t11;

    const int4 sv = *reinterpret_cast<const int4*>(lx + 4*idx);
    int s0 = sv.x, s1 = sv.y, s2 = sv.z, s3 = sv.w;
    int dm = (d == 0) ? L-1 : d-1;
    int hm = (h == 0) ? L-1 : h-1;
    int wm = (w == 0) ? L-1 : w-1;
    int r1 = lx[4*((dm*L + h)*L + w) + 1];
    int r2 = lx[4*((d*L + hm)*L + w) + 2];
    int r3 = lx[4*((d*L + h)*L + wm) + 3];

    auto dot = [&](int a, int b) -> float {
        return (a == b) ? (a ? d11 : d00) : d01;
    };

    union { unsigned short s[16]; int4 q[2]; } u;
    u.s[0]  = f2bf(dot(s0, s1));
    u.s[1]  = f2bf(dot(s0, s2));
    u.s[2]  = f2bf(dot(s0, s3));
    u.s[3]  = f2bf(dot(s0, r1));
    u.s[4]  = f2bf(dot(s0, r2));
    u.s[5]  = f2bf(dot(s0, r3));
    u.s[6]  = f2bf(dot(s1, s2));
    u.s[7]  = f2bf(dot(s2, s3));
    u.s[8]  = f2bf(dot(s3, s1));
    u.s[9]  = f2bf(dot(r1, r2));
    u.s[10] = f2bf(dot(r2, r3));
    u.s[11] = f2bf(dot(r3, r1));
    u.s[12] = 0; u.s[13] = 0; u.s[14] = 0; u.s[15] = 0;

    int4* dst = reinterpret_cast<int4*>(bnd + (size_t)idx*16);
    dst[0] = u.q[0];
    dst[1] = u.q[1];
}

// ---- stage 6x6x18 halo tile via async global->LDS DMA ----
__device__ __forceinline__ void stage_tile(
    const unsigned short* __restrict__ x, unsigned short* __restrict__ tile,
    int W0, int H0, int D0, int tid)
{
    #pragma unroll
    for (int i = 0; i < 6; ++i) {
        int t = tid + i*256;
        if (i < 5 || t < 1296) {
            int row = t / 36, off = t - row*36;     // row = dd*6+hh, off = vox*2+half
            int dd = row / 6, hh = row - dd*6;
            int gd = wrapc(D0 + dd - 1);
            int gh = wrapc(H0 + hh - 1);
            int vox = off >> 1, half = off & 1;
            int gw = wrapc(W0 + vox - 1);
            size_t gi = ((size_t)((gd*L + gh)*L + gw))*16 + half*8;
            __builtin_amdgcn_global_load_lds(
                (const __attribute__((address_space(1))) unsigned int*)(x + gi),
                (__attribute__((address_space(3))) unsigned int*)(tile + t*8),
                16, 0, 0);
        }
    }
}

// ---- conv1: 16ch (12 live) -> 16ch, B in LDS, depth-1 prefetch ----
__global__ __launch_bounds__(256, 4) void conv1_kernel(
    const unsigned short* __restrict__ x, const unsigned short* __restrict__ Bm,
    const float* __restrict__ bias, unsigned short* __restrict__ y)
{
    __shared__ unsigned short tile[6*6*18*16];   // 20736 B
    __shared__ unsigned short Bls[16*BSTRIDE];   // 14592 B
    int tid = threadIdx.x;
    int W0 = blockIdx.x * 16, H0 = blockIdx.y * 4, D0 = blockIdx.z * 4;

    stage_tile(x, tile, W0, H0, D0, tid);
    // copy B: 16 rows x 56 int4
    #pragma unroll
    for (int i = 0; i < 4; ++i) {
        int t = tid + i*256;
        if (i < 3 || t < 896) {
            int row = t / 56, col = t - row*56;
            *reinterpret_cast<int4*>(&Bls[row*BSTRIDE + col*8]) =
                *reinterpret_cast<const int4*>(&Bm[row*448 + col*8]);
        }
    }
    __syncthreads();

    int lane = tid & 63, wave = tid >> 6;
    int laneV = lane & 15, g = lane >> 4;

    floatx4 acc[4];
    #pragma unroll
    for (int m = 0; m < 4; ++m) acc[m] = (floatx4)(0.0f);

    int moff[4];
    #pragma unroll
    for (int m = 0; m < 4; ++m) {
        int mt = wave*4 + m;                      // dd = mt>>2, hh = mt&3
        moff[m] = (((mt >> 2)*6 + (mt & 3))*18)*16;
    }

    auto aoff_of = [&](int kt) {
        int tau = 2*kt + (g >> 1);
        if (tau > 26) tau = 26;
        int kd = tau / 9;
        int r  = tau - kd*9;
        int kh = r / 3;
        int kw = r - kh*3;
        return ((kd*6 + kh)*18 + kw + laneV)*16 + (g & 1)*8;
    };

    short8 aC[4], aN[4], bC, bN;
    {
        int a0 = aoff_of(0);
        bC = *reinterpret_cast<const short8*>(&Bls[laneV*BSTRIDE + g*8]);
        #pragma unroll
        for (int m = 0; m < 4; ++m)
            aC[m] = *reinterpret_cast<const short8*>(&tile[moff[m] + a0]);
    }

    #pragma unroll
    for (int kt = 0; kt < 14; ++kt) {
        if (kt < 13) {
            int an = aoff_of(kt+1);
            bN = *reinterpret_cast<const short8*>(&Bls[laneV*BSTRIDE + (kt+1)*32 + g*8]);
            #pragma unroll
            for (int m = 0; m < 4; ++m)
                aN[m] = *reinterpret_cast<const short8*>(&tile[moff[m] + an]);
        }
        #pragma unroll
        for (int m = 0; m < 4; ++m)
            acc[m] = __builtin_amdgcn_mfma_f32_16x16x32_bf16(aC[m], bC, acc[m], 0, 0, 0);
        if (kt < 13) {
            #pragma unroll
            for (int m = 0; m < 4; ++m) aC[m] = aN[m];
            bC = bN;
        }
    }

    float bch = bias[laneV];
    #pragma unroll
    for (int m = 0; m < 4; ++m) {
        int mt = wave*4 + m;
        int d = D0 + (mt >> 2), h = H0 + (mt & 3);
        int wb = W0 + g*4;                       // D row = quad*4 + reg
        size_t base = ((size_t)((d*L + h)*L + wb))*16 + laneV;
        #pragma unroll
        for (int reg = 0; reg < 4; ++reg) {
            y[base + (size_t)reg*16] = f2bf(eluf(acc[m][reg] + bch));
        }
    }
}

// ---- conv2: 16 -> 32, B in LDS, depth-1 prefetch, fused reduce + atomic ----
__global__ __launch_bounds__(256, 4) void conv2_kernel(
    const unsigned short* __restrict__ x, const unsigned short* __restrict__ Bm,
    const float* __restrict__ bias, const float* __restrict__ wd,
    float* __restrict__ out)
{
    __shared__ unsigned short tile[6*6*18*16];   // 20736 B
    __shared__ unsigned short Bls[32*BSTRIDE];   // 29184 B
    __shared__ float red[4];
    int tid = threadIdx.x;
    int W0 = blockIdx.x * 16, H0 = blockIdx.y * 4, D0 = blockIdx.z * 4;

    stage_tile(x, tile, W0, H0, D0, tid);
    // copy B: 32 rows x 56 int4 = 1792 = 7*256
    #pragma unroll
    for (int i = 0; i < 7; ++i) {
        int t = tid + i*256;
        int row = t / 56, col = t - row*56;
        *reinterpret_cast<int4*>(&Bls[row*BSTRIDE + col*8]) =
            *reinterpret_cast<const int4*>(&Bm[row*448 + col*8]);
    }
    __syncthreads();

    int lane = tid & 63, wave = tid >> 6;
    int laneV = lane & 15, g = lane >> 4;

    floatx4 acc[4][2];
    #pragma unroll
    for (int m = 0; m < 4; ++m) {
        acc[m][0] = (floatx4)(0.0f);
        acc[m][1] = (floatx4)(0.0f);
    }

    int moff[4];
    #pragma unroll
    for (int m = 0; m < 4; ++m) {
        int mt = wave*4 + m;
        moff[m] = (((mt >> 2)*6 + (mt & 3))*18)*16;
    }

    auto aoff_of = [&](int kt) {
        int tau = 2*kt + (g >> 1);
        if (tau > 26) tau = 26;
        int kd = tau / 9;
        int r  = tau - kd*9;
        int kh = r / 3;
        int kw = r - kh*3;
        return ((kd*6 + kh)*18 + kw + laneV)*16 + (g & 1)*8;
    };

    short8 aC[4], aN[4], bC0, bC1, bN0, bN1;
    {
        int a0 = aoff_of(0);
        bC0 = *reinterpret_cast<const short8*>(&Bls[laneV*BSTRIDE + g*8]);
        bC1 = *reinterpret_cast<const short8*>(&Bls[(16 + laneV)*BSTRIDE + g*8]);
        #pragma unroll
        for (int m = 0; m < 4; ++m)
            aC[m] = *reinterpret_cast<const short8*>(&tile[moff[m] + a0]);
    }

    #pragma unroll
    for (int kt = 0; kt < 14; ++kt) {
        if (kt < 13) {
            int an = aoff_of(kt+1);
            bN0 = *reinterpret_cast<const short8*>(&Bls[laneV*BSTRIDE + (kt+1)*32 + g*8]);
            bN1 = *reinterpret_cast<const short8*>(&Bls[(16 + laneV)*BSTRIDE + (kt+1)*32 + g*8]);
            #pragma unroll
            for (int m = 0; m < 4; ++m)
                aN[m] = *reinterpret_cast<const short8*>(&tile[moff[m] + an]);
        }
        #pragma unroll
        for (int m = 0; m < 4; ++m) {
            acc[m][0] = __builtin_amdgcn_mfma_f32_16x16x32_bf16(aC[m], bC0, acc[m][0], 0, 0, 0);
            acc[m][1] = __builtin_amdgcn_mfma_f32_16x16x32_bf16(aC[m], bC1, acc[m][1], 0, 0, 0);
        }
        if (kt < 13) {
            #pragma unroll
            for (int m = 0; m < 4; ++m) aC[m] = aN[m];
            bC0 = bN0; bC1 = bN1;
        }
    }

    float b2a = bias[laneV], b2b = bias[16 + laneV];
    float wda = wd[laneV],  wdb = wd[16 + laneV];
    float s = 0.0f;
    #pragma unroll
    for (int m = 0; m < 4; ++m) {
        #pragma unroll
        for (int reg = 0; reg < 4; ++reg) {
            s += eluf(acc[m][0][reg] + b2a) * wda;
            s += eluf(acc[m][1][reg] + b2b) * wdb;
        }
    }

    #pragma unroll
    for (int off = 32; off; off >>= 1) s += __shfl_down(s, off);
    if (lane == 0) red[wave] = s;
    __syncthreads();
    if (tid == 0) {
        atomicAdd(out, (red[0] + red[1] + red[2] + red[3]) * (1.0f / (float)L3));
    }
}

extern "C" void kernel_launch(void* const* d_in, const int* in_sizes, int n_in,
                              void* d_out, int out_size, void* d_ws, size_t ws_size,
                              hipStream_t stream) {
    const int*   lx  = (const int*)  d_in[0];
    const float* tet = (const float*)d_in[1];
    const float* w1  = (const float*)d_in[2];
    const float* b1  = (const float*)d_in[3];
    const float* w2  = (const float*)d_in[4];
    const float* b2  = (const float*)d_in[5];
    const float* wd  = (const float*)d_in[6];
    float* out = (float*)d_out;

    char* ws = (char*)d_ws;
    const size_t ARR_BYTES = (size_t)L3 * 16 * 2;           // 28.3 MB
    unsigned short* bnd  = (unsigned short*)ws;
    unsigned short* y1   = (unsigned short*)(ws + ARR_BYTES);
    unsigned short* Bm1  = (unsigned short*)(ws + 2*ARR_BYTES);
    unsigned short* Bm2  = (unsigned short*)(ws + 2*ARR_BYTES + 16*448*2);

    hipMemsetAsync(out, 0, sizeof(float), stream);
    prep_kernel<<<L3/256, 256, 0, stream>>>(lx, tet, w1, w2, bnd, Bm1, Bm2);
    conv1_kernel<<<dim3(6,24,24), 256, 0, stream>>>(bnd, Bm1, b1, y1);
    conv2_kernel<<<dim3(6,24,24), 256, 0, stream>>>(y1, Bm2, b2, wd, out);
}

// Round 12
// 152.949 us; speedup vs baseline: 1.1910x; 1.1910x over previous
//
#include <hip/hip_runtime.h>
#include <hip/hip_bf16.h>
#include <cmath>

#define L 96
#define L3 (L*L*L)
#define NCONV 3456   // 6*24*24 conv workgroups

// B-in-LDS row stride: 456 shorts (912 B) -> measured conflict-free (R8).
#define BSTRIDE 456

typedef __attribute__((ext_vector_type(8))) short short8;
typedef __attribute__((ext_vector_type(4))) float floatx4;

__device__ __forceinline__ float eluf(float x) {
    float e = __expf(x) - 1.0f;
    return x > 0.0f ? x : e;
}

__device__ __forceinline__ unsigned short f2bf(float f) {
    __hip_bfloat16 h = __float2bfloat16(f);
    return *reinterpret_cast<unsigned short*>(&h);
}

// wrap into [0,96) for x in [-1, 97)
__device__ __forceinline__ int wrapc(int x) {
    if (x < 0) x += L;
    if (x >= L) x -= L;
    return x;
}

// ---- fused: bonds (all 3456 blocks) + weight reorder (blocks 0-83) ----
__global__ __launch_bounds__(256) void prep_kernel(
    const int* __restrict__ lx, const float* __restrict__ tet,
    const float* __restrict__ w1, const float* __restrict__ w2,
    unsigned short* __restrict__ bnd,
    unsigned short* __restrict__ Bm1, unsigned short* __restrict__ Bm2)
{
    int idx = blockIdx.x * 256 + threadIdx.x;

    // weight reorder: Bmat[N][K=448], K = tap*16 + ch, zero-padded
    if (idx < 16*448) {
        int o = idx / 448, k = idx % 448;
        int tau = k >> 4, i = k & 15;
        float v = (tau < 27 && i < 12) ? w1[tau*192 + i*16 + o] : 0.0f;
        Bm1[o*448 + k] = f2bf(v);
    }
    int j = idx - 16*448;
    if (j >= 0 && j < 32*448) {
        int o = j / 448, k = j % 448;
        int tau = k >> 4;
        int i = k & 15;
        float v = (tau < 27) ? w2[tau*512 + i*32 + o] : 0.0f;
        Bm2[o*448 + k] = f2bf(v);
    }

    // bonds: spins -> unpadded bf16 [96^3][16], ch 12-15 = 0
    int w = idx % L;
    int t = idx / L;
    int h = t % L;
    int d = t / L;

    float t00 = tet[0], t01 = tet[1], t10 = tet[2], t11 = tet[3];
    float d00 = t00*t00 + t01*t01;
    float d01 = t00*t10 + t01*t11;
    float d11 = t10*t10 + t11*t11;

    const int4 sv = *reinterpret_cast<const int4*>(lx + 4*idx);
    int s0 = sv.x, s1 = sv.y, s2 = sv.z, s3 = sv.w;
    int dm = (d == 0) ? L-1 : d-1;
    int hm = (h == 0) ? L-1 : h-1;
    int wm = (w == 0) ? L-1 : w-1;
    int r1 = lx[4*((dm*L + h)*L + w) + 1];
    int r2 = lx[4*((d*L + hm)*L + w) + 2];
    int r3 = lx[4*((d*L + h)*L + wm) + 3];

    auto dot = [&](int a, int b) -> float {
        return (a == b) ? (a ? d11 : d00) : d01;
    };

    union { unsigned short s[16]; int4 q[2]; } u;
    u.s[0]  = f2bf(dot(s0, s1));
    u.s[1]  = f2bf(dot(s0, s2));
    u.s[2]  = f2bf(dot(s0, s3));
    u.s[3]  = f2bf(dot(s0, r1));
    u.s[4]  = f2bf(dot(s0, r2));
    u.s[5]  = f2bf(dot(s0, r3));
    u.s[6]  = f2bf(dot(s1, s2));
    u.s[7]  = f2bf(dot(s2, s3));
    u.s[8]  = f2bf(dot(s3, s1));
    u.s[9]  = f2bf(dot(r1, r2));
    u.s[10] = f2bf(dot(r2, r3));
    u.s[11] = f2bf(dot(r3, r1));
    u.s[12] = 0; u.s[13] = 0; u.s[14] = 0; u.s[15] = 0;

    int4* dst = reinterpret_cast<int4*>(bnd + (size_t)idx*16);
    dst[0] = u.q[0];
    dst[1] = u.q[1];
}

// ---- stage 6x6x18 halo tile via async global->LDS DMA ----
__device__ __forceinline__ void stage_tile(
    const unsigned short* __restrict__ x, unsigned short* __restrict__ tile,
    int W0, int H0, int D0, int tid)
{
    #pragma unroll
    for (int i = 0; i < 6; ++i) {
        int t = tid + i*256;
        if (i < 5 || t < 1296) {
            int row = t / 36, off = t - row*36;     // row = dd*6+hh, off = vox*2+half
            int dd = row / 6, hh = row - dd*6;
            int gd = wrapc(D0 + dd - 1);
            int gh = wrapc(H0 + hh - 1);
            int vox = off >> 1, half = off & 1;
            int gw = wrapc(W0 + vox - 1);
            size_t gi = ((size_t)((gd*L + gh)*L + gw))*16 + half*8;
            __builtin_amdgcn_global_load_lds(
                (const __attribute__((address_space(1))) unsigned int*)(x + gi),
                (__attribute__((address_space(3))) unsigned int*)(tile + t*8),
                16, 0, 0);
        }
    }
}

// ---- conv1: 16ch (12 live) -> 16ch, B in LDS, depth-1 prefetch ----
__global__ __launch_bounds__(256, 4) void conv1_kernel(
    const unsigned short* __restrict__ x, const unsigned short* __restrict__ Bm,
    const float* __restrict__ bias, unsigned short* __restrict__ y)
{
    __shared__ unsigned short tile[6*6*18*16];   // 20736 B
    __shared__ unsigned short Bls[16*BSTRIDE];   // 14592 B
    int tid = threadIdx.x;
    int W0 = blockIdx.x * 16, H0 = blockIdx.y * 4, D0 = blockIdx.z * 4;

    stage_tile(x, tile, W0, H0, D0, tid);
    // copy B: 16 rows x 56 int4
    #pragma unroll
    for (int i = 0; i < 4; ++i) {
        int t = tid + i*256;
        if (i < 3 || t < 896) {
            int row = t / 56, col = t - row*56;
            *reinterpret_cast<int4*>(&Bls[row*BSTRIDE + col*8]) =
                *reinterpret_cast<const int4*>(&Bm[row*448 + col*8]);
        }
    }
    __syncthreads();

    int lane = tid & 63, wave = tid >> 6;
    int laneV = lane & 15, g = lane >> 4;

    floatx4 acc[4];
    #pragma unroll
    for (int m = 0; m < 4; ++m) acc[m] = (floatx4)(0.0f);

    int moff[4];
    #pragma unroll
    for (int m = 0; m < 4; ++m) {
        int mt = wave*4 + m;                      // dd = mt>>2, hh = mt&3
        moff[m] = (((mt >> 2)*6 + (mt & 3))*18)*16;
    }

    auto aoff_of = [&](int kt) {
        int tau = 2*kt + (g >> 1);
        if (tau > 26) tau = 26;
        int kd = tau / 9;
        int r  = tau - kd*9;
        int kh = r / 3;
        int kw = r - kh*3;
        return ((kd*6 + kh)*18 + kw + laneV)*16 + (g & 1)*8;
    };

    short8 aC[4], aN[4], bC, bN;
    {
        int a0 = aoff_of(0);
        bC = *reinterpret_cast<const short8*>(&Bls[laneV*BSTRIDE + g*8]);
        #pragma unroll
        for (int m = 0; m < 4; ++m)
            aC[m] = *reinterpret_cast<const short8*>(&tile[moff[m] + a0]);
    }

    #pragma unroll
    for (int kt = 0; kt < 14; ++kt) {
        if (kt < 13) {
            int an = aoff_of(kt+1);
            bN = *reinterpret_cast<const short8*>(&Bls[laneV*BSTRIDE + (kt+1)*32 + g*8]);
            #pragma unroll
            for (int m = 0; m < 4; ++m)
                aN[m] = *reinterpret_cast<const short8*>(&tile[moff[m] + an]);
        }
        #pragma unroll
        for (int m = 0; m < 4; ++m)
            acc[m] = __builtin_amdgcn_mfma_f32_16x16x32_bf16(aC[m], bC, acc[m], 0, 0, 0);
        if (kt < 13) {
            #pragma unroll
            for (int m = 0; m < 4; ++m) aC[m] = aN[m];
            bC = bN;
        }
    }

    float bch = bias[laneV];
    #pragma unroll
    for (int m = 0; m < 4; ++m) {
        int mt = wave*4 + m;
        int d = D0 + (mt >> 2), h = H0 + (mt & 3);
        int wb = W0 + g*4;                       // D row = quad*4 + reg
        size_t base = ((size_t)((d*L + h)*L + wb))*16 + laneV;
        #pragma unroll
        for (int reg = 0; reg < 4; ++reg) {
            y[base + (size_t)reg*16] = f2bf(eluf(acc[m][reg] + bch));
        }
    }
}

// ---- conv2: 16 -> 32, B in LDS, depth-1 prefetch, fused reduce ----
__global__ __launch_bounds__(256, 4) void conv2_kernel(
    const unsigned short* __restrict__ x, const unsigned short* __restrict__ Bm,
    const float* __restrict__ bias, const float* __restrict__ wd,
    float* __restrict__ partials)
{
    __shared__ unsigned short tile[6*6*18*16];   // 20736 B
    __shared__ unsigned short Bls[32*BSTRIDE];   // 29184 B
    __shared__ float red[4];
    int tid = threadIdx.x;
    int W0 = blockIdx.x * 16, H0 = blockIdx.y * 4, D0 = blockIdx.z * 4;

    stage_tile(x, tile, W0, H0, D0, tid);
    // copy B: 32 rows x 56 int4 = 1792 = 7*256
    #pragma unroll
    for (int i = 0; i < 7; ++i) {
        int t = tid + i*256;
        int row = t / 56, col = t - row*56;
        *reinterpret_cast<int4*>(&Bls[row*BSTRIDE + col*8]) =
            *reinterpret_cast<const int4*>(&Bm[row*448 + col*8]);
    }
    __syncthreads();

    int lane = tid & 63, wave = tid >> 6;
    int laneV = lane & 15, g = lane >> 4;

    floatx4 acc[4][2];
    #pragma unroll
    for (int m = 0; m < 4; ++m) {
        acc[m][0] = (floatx4)(0.0f);
        acc[m][1] = (floatx4)(0.0f);
    }

    int moff[4];
    #pragma unroll
    for (int m = 0; m < 4; ++m) {
        int mt = wave*4 + m;
        moff[m] = (((mt >> 2)*6 + (mt & 3))*18)*16;
    }

    auto aoff_of = [&](int kt) {
        int tau = 2*kt + (g >> 1);
        if (tau > 26) tau = 26;
        int kd = tau / 9;
        int r  = tau - kd*9;
        int kh = r / 3;
        int kw = r - kh*3;
        return ((kd*6 + kh)*18 + kw + laneV)*16 + (g & 1)*8;
    };

    short8 aC[4], aN[4], bC0, bC1, bN0, bN1;
    {
        int a0 = aoff_of(0);
        bC0 = *reinterpret_cast<const short8*>(&Bls[laneV*BSTRIDE + g*8]);
        bC1 = *reinterpret_cast<const short8*>(&Bls[(16 + laneV)*BSTRIDE + g*8]);
        #pragma unroll
        for (int m = 0; m < 4; ++m)
            aC[m] = *reinterpret_cast<const short8*>(&tile[moff[m] + a0]);
    }

    #pragma unroll
    for (int kt = 0; kt < 14; ++kt) {
        if (kt < 13) {
            int an = aoff_of(kt+1);
            bN0 = *reinterpret_cast<const short8*>(&Bls[laneV*BSTRIDE + (kt+1)*32 + g*8]);
            bN1 = *reinterpret_cast<const short8*>(&Bls[(16 + laneV)*BSTRIDE + (kt+1)*32 + g*8]);
            #pragma unroll
            for (int m = 0; m < 4; ++m)
                aN[m] = *reinterpret_cast<const short8*>(&tile[moff[m] + an]);
        }
        #pragma unroll
        for (int m = 0; m < 4; ++m) {
            acc[m][0] = __builtin_amdgcn_mfma_f32_16x16x32_bf16(aC[m], bC0, acc[m][0], 0, 0, 0);
            acc[m][1] = __builtin_amdgcn_mfma_f32_16x16x32_bf16(aC[m], bC1, acc[m][1], 0, 0, 0);
        }
        if (kt < 13) {
            #pragma unroll
            for (int m = 0; m < 4; ++m) aC[m] = aN[m];
            bC0 = bN0; bC1 = bN1;
        }
    }

    float b2a = bias[laneV], b2b = bias[16 + laneV];
    float wda = wd[laneV],  wdb = wd[16 + laneV];
    float s = 0.0f;
    #pragma unroll
    for (int m = 0; m < 4; ++m) {
        #pragma unroll
        for (int reg = 0; reg < 4; ++reg) {
            s += eluf(acc[m][0][reg] + b2a) * wda;
            s += eluf(acc[m][1][reg] + b2b) * wdb;
        }
    }

    #pragma unroll
    for (int off = 32; off; off >>= 1) s += __shfl_down(s, off);
    if (lane == 0) red[wave] = s;
    __syncthreads();
    if (tid == 0) {
        int bid = (blockIdx.z * gridDim.y + blockIdx.y) * gridDim.x + blockIdx.x;
        partials[bid] = red[0] + red[1] + red[2] + red[3];
    }
}

// ---- final reduce ----
__global__ __launch_bounds__(256) void final_kernel(
    const float* __restrict__ partials, float* __restrict__ out)
{
    float s = 0.0f;
    for (int i = threadIdx.x; i < NCONV; i += 256) s += partials[i];
    #pragma unroll
    for (int off = 32; off; off >>= 1) s += __shfl_down(s, off);
    __shared__ float red[4];
    int lane = threadIdx.x & 63;
    int wv   = threadIdx.x >> 6;
    if (lane == 0) red[wv] = s;
    __syncthreads();
    if (threadIdx.x == 0)
        out[0] = (red[0] + red[1] + red[2] + red[3]) * (1.0f / (float)L3);
}

extern "C" void kernel_launch(void* const* d_in, const int* in_sizes, int n_in,
                              void* d_out, int out_size, void* d_ws, size_t ws_size,
                              hipStream_t stream) {
    const int*   lx  = (const int*)  d_in[0];
    const float* tet = (const float*)d_in[1];
    const float* w1  = (const float*)d_in[2];
    const float* b1  = (const float*)d_in[3];
    const float* w2  = (const float*)d_in[4];
    const float* b2  = (const float*)d_in[5];
    const float* wd  = (const float*)d_in[6];
    float* out = (float*)d_out;

    char* ws = (char*)d_ws;
    const size_t ARR_BYTES = (size_t)L3 * 16 * 2;           // 28.3 MB
    unsigned short* bnd  = (unsigned short*)ws;
    unsigned short* y1   = (unsigned short*)(ws + ARR_BYTES);
    unsigned short* Bm1  = (unsigned short*)(ws + 2*ARR_BYTES);
    unsigned short* Bm2  = (unsigned short*)(ws + 2*ARR_BYTES + 16*448*2);
    float* partials      = (float*)         (ws + 2*ARR_BYTES + 48*448*2);

    prep_kernel<<<L3/256, 256, 0, stream>>>(lx, tet, w1, w2, bnd, Bm1, Bm2);
    conv1_kernel<<<dim3(6,24,24), 256, 0, stream>>>(bnd, Bm1, b1, y1);
    conv2_kernel<<<dim3(6,24,24), 256, 0, stream>>>(y1, Bm2, b2, wd, partials);
    final_kernel<<<1, 256, 0, stream>>>(partials, out);
}

// Round 13
// 144.877 us; speedup vs baseline: 1.2574x; 1.0557x over previous
//
#include <hip/hip_runtime.h>
#include <hip/hip_bf16.h>
#include <cmath>

#define L 96
#define L3 (L*L*L)
#define NCONV 3456   // 6*24*24 conv workgroups

// B rows padded to 456 shorts (912 B = 57*16B): conflict-free LDS reads (R8)
// AND 16B-aligned rows so the whole B matrix DMA-copies linearly.
#define BSTRIDE 456

// tap -> tile byte-offset/16 table: TAU[tau] = ((kd*6+kh)*18+kw)*16
__device__ __constant__ const int TAU[27] = {
    0,16,32, 288,304,320, 576,592,608,
    1728,1744,1760, 2016,2032,2048, 2304,2320,2336,
    3456,3472,3488, 3744,3760,3776, 4032,4048,4064};

typedef __attribute__((ext_vector_type(8))) short short8;
typedef __attribute__((ext_vector_type(4))) float floatx4;

__device__ __forceinline__ float eluf(float x) {
    float e = __expf(x) - 1.0f;
    return x > 0.0f ? x : e;
}

__device__ __forceinline__ unsigned short f2bf(float f) {
    __hip_bfloat16 h = __float2bfloat16(f);
    return *reinterpret_cast<unsigned short*>(&h);
}

// wrap into [0,96) for x in [-1, 97)
__device__ __forceinline__ int wrapc(int x) {
    if (x < 0) x += L;
    if (x >= L) x -= L;
    return x;
}

// ---- fused: bonds (all blocks) + weight reorder to padded stride (blocks 0-85) ----
__global__ __launch_bounds__(256) void prep_kernel(
    const int* __restrict__ lx, const float* __restrict__ tet,
    const float* __restrict__ w1, const float* __restrict__ w2,
    unsigned short* __restrict__ bnd,
    unsigned short* __restrict__ Bm1, unsigned short* __restrict__ Bm2)
{
    int idx = blockIdx.x * 256 + threadIdx.x;

    // weight reorder: Bmat[N][K], K-stride 456 (448 live + 8 zero pad)
    if (idx < 16*BSTRIDE) {
        int o = idx / BSTRIDE, k = idx % BSTRIDE;
        int tau = k >> 4, i = k & 15;
        float v = (k < 448 && tau < 27 && i < 12) ? w1[tau*192 + i*16 + o] : 0.0f;
        Bm1[idx] = f2bf(v);
    }
    int j = idx - 16*BSTRIDE;
    if (j >= 0 && j < 32*BSTRIDE) {
        int o = j / BSTRIDE, k = j % BSTRIDE;
        int tau = k >> 4;
        int i = k & 15;
        float v = (k < 448 && tau < 27) ? w2[tau*512 + i*32 + o] : 0.0f;
        Bm2[j] = f2bf(v);
    }

    // bonds: spins -> unpadded bf16 [96^3][16], ch 12-15 = 0
    int w = idx % L;
    int t = idx / L;
    int h = t % L;
    int d = t / L;

    float t00 = tet[0], t01 = tet[1], t10 = tet[2], t11 = tet[3];
    float d00 = t00*t00 + t01*t01;
    float d01 = t00*t10 + t01*t11;
    float d11 = t10*t10 + t11*t11;

    const int4 sv = *reinterpret_cast<const int4*>(lx + 4*idx);
    int s0 = sv.x, s1 = sv.y, s2 = sv.z, s3 = sv.w;
    int dm = (d == 0) ? L-1 : d-1;
    int hm = (h == 0) ? L-1 : h-1;
    int wm = (w == 0) ? L-1 : w-1;
    int r1 = lx[4*((dm*L + h)*L + w) + 1];
    int r2 = lx[4*((d*L + hm)*L + w) + 2];
    int r3 = lx[4*((d*L + h)*L + wm) + 3];

    auto dot = [&](int a, int b) -> float {
        return (a == b) ? (a ? d11 : d00) : d01;
    };

    union { unsigned short s[16]; int4 q[2]; } u;
    u.s[0]  = f2bf(dot(s0, s1));
    u.s[1]  = f2bf(dot(s0, s2));
    u.s[2]  = f2bf(dot(s0, s3));
    u.s[3]  = f2bf(dot(s0, r1));
    u.s[4]  = f2bf(dot(s0, r2));
    u.s[5]  = f2bf(dot(s0, r3));
    u.s[6]  = f2bf(dot(s1, s2));
    u.s[7]  = f2bf(dot(s2, s3));
    u.s[8]  = f2bf(dot(s3, s1));
    u.s[9]  = f2bf(dot(r1, r2));
    u.s[10] = f2bf(dot(r2, r3));
    u.s[11] = f2bf(dot(r3, r1));
    u.s[12] = 0; u.s[13] = 0; u.s[14] = 0; u.s[15] = 0;

    int4* dst = reinterpret_cast<int4*>(bnd + (size_t)idx*16);
    dst[0] = u.q[0];
    dst[1] = u.q[1];
}

// ---- stage 6x6x18 halo tile via async global->LDS DMA ----
__device__ __forceinline__ void stage_tile(
    const unsigned short* __restrict__ x, unsigned short* __restrict__ tile,
    int W0, int H0, int D0, int tid)
{
    #pragma unroll
    for (int i = 0; i < 6; ++i) {
        int t = tid + i*256;
        if (i < 5 || t < 1296) {
            int row = t / 36, off = t - row*36;     // row = dd*6+hh, off = vox*2+half
            int dd = row / 6, hh = row - dd*6;
            int gd = wrapc(D0 + dd - 1);
            int gh = wrapc(H0 + hh - 1);
            int vox = off >> 1, half = off & 1;
            int gw = wrapc(W0 + vox - 1);
            size_t gi = ((size_t)((gd*L + gh)*L + gw))*16 + half*8;
            __builtin_amdgcn_global_load_lds(
                (const __attribute__((address_space(1))) unsigned int*)(x + gi),
                (__attribute__((address_space(3))) unsigned int*)(tile + t*8),
                16, 0, 0);
        }
    }
}

// ---- linear B-matrix DMA: n16 * 456 shorts, 16 B per transfer ----
__device__ __forceinline__ void stage_bmat(
    const unsigned short* __restrict__ Bm, unsigned short* __restrict__ Bls,
    int nxfer, int tid)
{
    #pragma unroll
    for (int i = 0; i < 8; ++i) {
        int t = tid + i*256;
        if (t < nxfer) {
            __builtin_amdgcn_global_load_lds(
                (const __attribute__((address_space(1))) unsigned int*)(Bm + t*8),
                (__attribute__((address_space(3))) unsigned int*)(Bls + t*8),
                16, 0, 0);
        }
    }
}

// ---- conv1: 16ch (12 live) -> 16ch, B in LDS, depth-1 prefetch ----
__global__ __launch_bounds__(256, 4) void conv1_kernel(
    const unsigned short* __restrict__ x, const unsigned short* __restrict__ Bm,
    const float* __restrict__ bias, unsigned short* __restrict__ y)
{
    __shared__ __attribute__((aligned(16))) unsigned short tile[6*6*18*16]; // 20736 B
    __shared__ __attribute__((aligned(16))) unsigned short Bls[16*BSTRIDE]; // 14592 B
    int tid = threadIdx.x;
    int W0 = blockIdx.x * 16, H0 = blockIdx.y * 4, D0 = blockIdx.z * 4;

    stage_tile(x, tile, W0, H0, D0, tid);
    stage_bmat(Bm, Bls, 912, tid);      // 16*456/8
    __syncthreads();

    int lane = tid & 63, wave = tid >> 6;
    int laneV = lane & 15, g = lane >> 4;
    int gb = g >> 1;
    int abase = laneV*16 + (g & 1)*8;

    floatx4 acc[4];
    #pragma unroll
    for (int m = 0; m < 4; ++m) acc[m] = (floatx4)(0.0f);

    int moff[4];
    #pragma unroll
    for (int m = 0; m < 4; ++m) {
        int mt = wave*4 + m;                      // dd = mt>>2, hh = mt&3
        moff[m] = (((mt >> 2)*6 + (mt & 3))*18)*16;
    }

    short8 aC[4], aN[4], bC, bN;
    {
        int a0 = abase + (gb ? TAU[1] : TAU[0]);
        bC = *reinterpret_cast<const short8*>(&Bls[laneV*BSTRIDE + g*8]);
        #pragma unroll
        for (int m = 0; m < 4; ++m)
            aC[m] = *reinterpret_cast<const short8*>(&tile[moff[m] + a0]);
    }

    #pragma unroll
    for (int kt = 0; kt < 14; ++kt) {
        if (kt < 13) {
            int tev = TAU[2*(kt+1)];
            int tod = TAU[(2*(kt+1)+1 > 26) ? 26 : 2*(kt+1)+1];
            int an = abase + (gb ? tod : tev);
            bN = *reinterpret_cast<const short8*>(&Bls[laneV*BSTRIDE + (kt+1)*32 + g*8]);
            #pragma unroll
            for (int m = 0; m < 4; ++m)
                aN[m] = *reinterpret_cast<const short8*>(&tile[moff[m] + an]);
        }
        #pragma unroll
        for (int m = 0; m < 4; ++m)
            acc[m] = __builtin_amdgcn_mfma_f32_16x16x32_bf16(aC[m], bC, acc[m], 0, 0, 0);
        if (kt < 13) {
            #pragma unroll
            for (int m = 0; m < 4; ++m) aC[m] = aN[m];
            bC = bN;
        }
    }

    float bch = bias[laneV];
    #pragma unroll
    for (int m = 0; m < 4; ++m) {
        int mt = wave*4 + m;
        int d = D0 + (mt >> 2), h = H0 + (mt & 3);
        int wb = W0 + g*4;                       // D row = quad*4 + reg
        size_t base = ((size_t)((d*L + h)*L + wb))*16 + laneV;
        #pragma unroll
        for (int reg = 0; reg < 4; ++reg) {
            y[base + (size_t)reg*16] = f2bf(eluf(acc[m][reg] + bch));
        }
    }
}

// ---- conv2: 16 -> 32, B in LDS, depth-1 prefetch, fused reduce ----
__global__ __launch_bounds__(256, 4) void conv2_kernel(
    const unsigned short* __restrict__ x, const unsigned short* __restrict__ Bm,
    const float* __restrict__ bias, const float* __restrict__ wd,
    float* __restrict__ partials)
{
    __shared__ __attribute__((aligned(16))) unsigned short tile[6*6*18*16]; // 20736 B
    __shared__ __attribute__((aligned(16))) unsigned short Bls[32*BSTRIDE]; // 29184 B
    __shared__ float red[4];
    int tid = threadIdx.x;
    int W0 = blockIdx.x * 16, H0 = blockIdx.y * 4, D0 = blockIdx.z * 4;

    stage_tile(x, tile, W0, H0, D0, tid);
    stage_bmat(Bm, Bls, 1824, tid);     // 32*456/8
    __syncthreads();

    int lane = tid & 63, wave = tid >> 6;
    int laneV = lane & 15, g = lane >> 4;
    int gb = g >> 1;
    int abase = laneV*16 + (g & 1)*8;

    floatx4 acc[4][2];
    #pragma unroll
    for (int m = 0; m < 4; ++m) {
        acc[m][0] = (floatx4)(0.0f);
        acc[m][1] = (floatx4)(0.0f);
    }

    int moff[4];
    #pragma unroll
    for (int m = 0; m < 4; ++m) {
        int mt = wave*4 + m;
        moff[m] = (((mt >> 2)*6 + (mt & 3))*18)*16;
    }

    short8 aC[4], aN[4], bC0, bC1, bN0, bN1;
    {
        int a0 = abase + (gb ? TAU[1] : TAU[0]);
        bC0 = *reinterpret_cast<const short8*>(&Bls[laneV*BSTRIDE + g*8]);
        bC1 = *reinterpret_cast<const short8*>(&Bls[(16 + laneV)*BSTRIDE + g*8]);
        #pragma unroll
        for (int m = 0; m < 4; ++m)
            aC[m] = *reinterpret_cast<const short8*>(&tile[moff[m] + a0]);
    }

    #pragma unroll
    for (int kt = 0; kt < 14; ++kt) {
        if (kt < 13) {
            int tev = TAU[2*(kt+1)];
            int tod = TAU[(2*(kt+1)+1 > 26) ? 26 : 2*(kt+1)+1];
            int an = abase + (gb ? tod : tev);
            bN0 = *reinterpret_cast<const short8*>(&Bls[laneV*BSTRIDE + (kt+1)*32 + g*8]);
            bN1 = *reinterpret_cast<const short8*>(&Bls[(16 + laneV)*BSTRIDE + (kt+1)*32 + g*8]);
            #pragma unroll
            for (int m = 0; m < 4; ++m)
                aN[m] = *reinterpret_cast<const short8*>(&tile[moff[m] + an]);
        }
        #pragma unroll
        for (int m = 0; m < 4; ++m) {
            acc[m][0] = __builtin_amdgcn_mfma_f32_16x16x32_bf16(aC[m], bC0, acc[m][0], 0, 0, 0);
            acc[m][1] = __builtin_amdgcn_mfma_f32_16x16x32_bf16(aC[m], bC1, acc[m][1], 0, 0, 0);
        }
        if (kt < 13) {
            #pragma unroll
            for (int m = 0; m < 4; ++m) aC[m] = aN[m];
            bC0 = bN0; bC1 = bN1;
        }
    }

    float b2a = bias[laneV], b2b = bias[16 + laneV];
    float wda = wd[laneV],  wdb = wd[16 + laneV];
    float s = 0.0f;
    #pragma unroll
    for (int m = 0; m < 4; ++m) {
        #pragma unroll
        for (int reg = 0; reg < 4; ++reg) {
            s += eluf(acc[m][0][reg] + b2a) * wda;
            s += eluf(acc[m][1][reg] + b2b) * wdb;
        }
    }

    #pragma unroll
    for (int off = 32; off; off >>= 1) s += __shfl_down(s, off);
    if (lane == 0) red[wave] = s;
    __syncthreads();
    if (tid == 0) {
        int bid = (blockIdx.z * gridDim.y + blockIdx.y) * gridDim.x + blockIdx.x;
        partials[bid] = red[0] + red[1] + red[2] + red[3];
    }
}

// ---- final reduce ----
__global__ __launch_bounds__(256) void final_kernel(
    const float* __restrict__ partials, float* __restrict__ out)
{
    float s = 0.0f;
    for (int i = threadIdx.x; i < NCONV; i += 256) s += partials[i];
    #pragma unroll
    for (int off = 32; off; off >>= 1) s += __shfl_down(s, off);
    __shared__ float red[4];
    int lane = threadIdx.x & 63;
    int wv   = threadIdx.x >> 6;
    if (lane == 0) red[wv] = s;
    __syncthreads();
    if (threadIdx.x == 0)
        out[0] = (red[0] + red[1] + red[2] + red[3]) * (1.0f / (float)L3);
}

extern "C" void kernel_launch(void* const* d_in, const int* in_sizes, int n_in,
                              void* d_out, int out_size, void* d_ws, size_t ws_size,
                              hipStream_t stream) {
    const int*   lx  = (const int*)  d_in[0];
    const float* tet = (const float*)d_in[1];
    const float* w1  = (const float*)d_in[2];
    const float* b1  = (const float*)d_in[3];
    const float* w2  = (const float*)d_in[4];
    const float* b2  = (const float*)d_in[5];
    const float* wd  = (const float*)d_in[6];
    float* out = (float*)d_out;

    char* ws = (char*)d_ws;
    const size_t ARR_BYTES = (size_t)L3 * 16 * 2;           // 28.3 MB
    unsigned short* bnd  = (unsigned short*)ws;
    unsigned short* y1   = (unsigned short*)(ws + ARR_BYTES);
    unsigned short* Bm1  = (unsigned short*)(ws + 2*ARR_BYTES);
    unsigned short* Bm2  = (unsigned short*)(ws + 2*ARR_BYTES + 16*BSTRIDE*2);
    float* partials      = (float*)         (ws + 2*ARR_BYTES + 48*BSTRIDE*2);

    prep_kernel<<<L3/256, 256, 0, stream>>>(lx, tet, w1, w2, bnd, Bm1, Bm2);
    conv1_kernel<<<dim3(6,24,24), 256, 0, stream>>>(bnd, Bm1, b1, y1);
    conv2_kernel<<<dim3(6,24,24), 256, 0, stream>>>(y1, Bm2, b2, wd, partials);
    final_kernel<<<1, 256, 0, stream>>>(partials, out);
}